// Round 1
// baseline (6669.213 us; speedup 1.0000x reference)
//
#include <hip/hip_runtime.h>
#include <hip/hip_bf16.h>

// Problem constants
#define BB 64
#define TT 1000
#define NI 4
#define HH 512
#define HH2 1024

__constant__ const float kDT = 0.01f;
// sqrt(2*DT*SIGMA_RECUR^2) = sqrt(5e-7), sqrt(2*DT*SIGMA_INPUT^2) = sqrt(5e-5)
#define PH_SCALE 7.0710678118654745e-4f
#define PI_SCALE 7.0710678118654745e-3f

typedef short s16x8 __attribute__((ext_vector_type(8)));
typedef float f32x4 __attribute__((ext_vector_type(4)));

// ---------------- Prologue: build bf16 W_rec (row-major [1024][1024]) ----------------
// W_rec = [[str2str, alm2str], [str2alm, alm2alm]]
__global__ __launch_bounds__(256) void build_w_kernel(
    const float* __restrict__ s2s, const float* __restrict__ a2a,
    const float* __restrict__ a2s, const float* __restrict__ s2a,
    __hip_bfloat16* __restrict__ Wb)
{
    int idx = blockIdx.x * 256 + threadIdx.x;   // [0, 1024*1024)
    int i = idx >> 10;
    int j = idx & 1023;
    float v;
    if (i < HH) v = (j < HH) ? s2s[i * HH + j]        : a2s[i * HH + (j - HH)];
    else        v = (j < HH) ? s2a[(i - HH) * HH + j] : a2a[(i - HH) * HH + (j - HH)];
    Wb[idx] = __float2bfloat16(v);
}

// ---------------- Prologue: init h (bf16) and x state (f32) ----------------
__global__ __launch_bounds__(256) void init_state_kernel(
    const float* __restrict__ hn, const float* __restrict__ x,
    __hip_bfloat16* __restrict__ h0, float* __restrict__ xs)
{
    int idx = blockIdx.x * 256 + threadIdx.x;   // [0, 65536)
    h0[idx] = __float2bfloat16(hn[idx]);
    xs[idx] = x[idx];
}

// ---------------- Per-timestep kernel ----------------
// Grid: 256 blocks x 64 threads (1 wave). Wave computes one 16x16 output tile:
//   mt = blockIdx >> 6 (b-tile 0..3), nt = blockIdx & 63 (i-tile 0..63)
// rec[b,i] = sum_j h_prev[b,j] * W[i,j]  via mfma_f32_16x16x32_bf16 over K=1024.
// A-frag: lane l -> h[mt*16 + (l&15)][kc*32 + (l>>4)*8 + e]  (8 consecutive bf16)
// B-frag: lane l -> W[nt*16 + (l&15)][kc*32 + (l>>4)*8 + e]
// C/D:    lane l, reg r -> row b = mt*16 + (l>>4)*4 + r, col i = nt*16 + (l&15)
__global__ __launch_bounds__(64) void step_kernel(
    const __hip_bfloat16* __restrict__ Wb,
    const __hip_bfloat16* __restrict__ h_prev,
    __hip_bfloat16* __restrict__ h_next,
    float* __restrict__ x_state,
    const float* __restrict__ inp,          // [B,T,4]
    const float* __restrict__ inhib,        // [B,1024]
    const float* __restrict__ perturb_hid,  // [T]
    const float* __restrict__ perturb_inp,  // [T]
    const float* __restrict__ inp_weight,   // [4,1024]
    float* __restrict__ rnn_out,            // [B,T,1024]
    float* __restrict__ x_out,              // [B,T,1024]
    int t)
{
    const int lane = threadIdx.x;
    const int nt = blockIdx.x & 63;
    const int mt = blockIdx.x >> 6;
    const int l15 = lane & 15;
    const int lq  = lane >> 4;

    const __hip_bfloat16* ap = h_prev + (mt * 16 + l15) * HH2 + lq * 8;
    const __hip_bfloat16* bp = Wb     + (nt * 16 + l15) * HH2 + lq * 8;

    f32x4 acc0 = {0.f, 0.f, 0.f, 0.f};
    f32x4 acc1 = {0.f, 0.f, 0.f, 0.f};
    #pragma unroll 8
    for (int kc = 0; kc < 32; kc += 2) {
        s16x8 a0 = *(const s16x8*)(ap + kc * 32);
        s16x8 b0 = *(const s16x8*)(bp + kc * 32);
        s16x8 a1 = *(const s16x8*)(ap + kc * 32 + 32);
        s16x8 b1 = *(const s16x8*)(bp + kc * 32 + 32);
        acc0 = __builtin_amdgcn_mfma_f32_16x16x32_bf16(a0, b0, acc0, 0, 0, 0);
        acc1 = __builtin_amdgcn_mfma_f32_16x16x32_bf16(a1, b1, acc1, 0, 0, 0);
    }

    const float phv = PH_SCALE * perturb_hid[t];
    const float piv = PI_SCALE * perturb_inp[t];
    const int i = nt * 16 + l15;
    const bool isStr = (i < HH);
    float iw0 = 0.f, iw1 = 0.f, iw2 = 0.f, iw3 = 0.f;
    if (isStr) {
        iw0 = inp_weight[0 * HH2 + i];
        iw1 = inp_weight[1 * HH2 + i];
        iw2 = inp_weight[2 * HH2 + i];
        iw3 = inp_weight[3 * HH2 + i];
    }

    #pragma unroll
    for (int r = 0; r < 4; ++r) {
        const int b = mt * 16 + lq * 4 + r;
        const float rec = acc0[r] + acc1[r];
        float drive = 0.f;
        if (isStr) {
            const float* ip = inp + (b * TT + t) * NI;
            drive = (ip[0] + piv) * iw0 + (ip[1] + piv) * iw1 +
                    (ip[2] + piv) * iw2 + (ip[3] + piv) * iw3;
        }
        const int si = b * HH2 + i;
        const float xp = x_state[si];
        const float xn = xp + kDT * (-xp + rec + drive + inhib[si]) + phv;
        const float hv = fmaxf(xn, 0.f);
        x_state[si] = xn;
        const size_t o = (size_t)(b * TT + t) * HH2 + i;
        x_out[o]   = xn;
        rnn_out[o] = hv;
        h_next[si] = __float2bfloat16(hv);
    }
}

// ---------------- fc1: out[b,t] = dot(rnn_out[b,t,512:1024], fc1_w[512:1024]) + fc1_b ----------------
// One wave per (b,t) row.
__global__ __launch_bounds__(256) void fc1_kernel(
    const float* __restrict__ rnn_out, const float* __restrict__ fc1_w,
    const float* __restrict__ fc1_b, float* __restrict__ out)
{
    const int wid = blockIdx.x * 4 + (threadIdx.x >> 6);  // [0, 64000)
    const int lane = threadIdx.x & 63;
    const float* p = rnn_out + (size_t)wid * HH2 + HH + lane * 8;
    const float* w = fc1_w + HH + lane * 8;
    f32x4 v0 = *(const f32x4*)(p);
    f32x4 v1 = *(const f32x4*)(p + 4);
    f32x4 w0 = *(const f32x4*)(w);
    f32x4 w1 = *(const f32x4*)(w + 4);
    float s = v0[0]*w0[0] + v0[1]*w0[1] + v0[2]*w0[2] + v0[3]*w0[3]
            + v1[0]*w1[0] + v1[1]*w1[1] + v1[2]*w1[2] + v1[3]*w1[3];
    #pragma unroll
    for (int off = 32; off; off >>= 1) s += __shfl_xor(s, off);
    if (lane == 0) out[wid] = s + fc1_b[0];
}

// ---------------- last-state extraction ----------------
__global__ __launch_bounds__(256) void last_kernel(
    const float* __restrict__ rnn_out, const float* __restrict__ x_out,
    float* __restrict__ hn_last, float* __restrict__ x_last)
{
    const int idx = blockIdx.x * 256 + threadIdx.x;  // [0, 65536)
    const int b = idx >> 10;
    const int i = idx & 1023;
    const size_t o = ((size_t)b * TT + (TT - 1)) * HH2 + i;
    hn_last[idx] = rnn_out[o];
    x_last[idx]  = x_out[o];
}

extern "C" void kernel_launch(void* const* d_in, const int* in_sizes, int n_in,
                              void* d_out, int out_size, void* d_ws, size_t ws_size,
                              hipStream_t stream) {
    const float* inp   = (const float*)d_in[0];   // [64,1000,4]
    const float* hn    = (const float*)d_in[1];   // [1,64,1024]
    const float* x     = (const float*)d_in[2];   // [1,64,1024]
    const float* inhib = (const float*)d_in[3];   // [64,1024]
    const float* ph    = (const float*)d_in[4];   // [1000]
    const float* pi    = (const float*)d_in[5];   // [1000]
    const float* s2s   = (const float*)d_in[6];   // [512,512]
    const float* a2a   = (const float*)d_in[7];
    const float* a2s   = (const float*)d_in[8];
    const float* s2a   = (const float*)d_in[9];
    const float* iw    = (const float*)d_in[10];  // [4,1024]
    const float* fw    = (const float*)d_in[11];  // [1,1024]
    const float* fb    = (const float*)d_in[12];  // [1]

    // Output tuple layout (floats): out | hn_last | rnn_out | x_last | x_out
    float* out     = (float*)d_out;               // 64000
    float* hn_last = out + 64000;                 // 65536
    float* rnn_out = out + 129536;                // 65,536,000
    float* x_last  = out + 65665536;              // 65536
    float* x_out   = out + 65731072;              // 65,536,000

    // Workspace layout: Wb (2 MB bf16) | h_buf[2] (2 x 128 KB bf16) | x_state (256 KB f32)
    char* ws = (char*)d_ws;
    __hip_bfloat16* Wb    = (__hip_bfloat16*)ws;
    __hip_bfloat16* hbuf0 = (__hip_bfloat16*)(ws + (1u << 21));
    __hip_bfloat16* hbuf1 = hbuf0 + 65536;
    float* xs             = (float*)(ws + (1u << 21) + (1u << 19));

    build_w_kernel<<<4096, 256, 0, stream>>>(s2s, a2a, a2s, s2a, Wb);
    init_state_kernel<<<256, 256, 0, stream>>>(hn, x, hbuf0, xs);

    for (int t = 0; t < TT; ++t) {
        const __hip_bfloat16* hp = (t & 1) ? hbuf1 : hbuf0;
        __hip_bfloat16*       hx = (t & 1) ? hbuf0 : hbuf1;
        step_kernel<<<256, 64, 0, stream>>>(Wb, hp, hx, xs, inp, inhib, ph, pi, iw,
                                            rnn_out, x_out, t);
    }

    fc1_kernel<<<16000, 256, 0, stream>>>(rnn_out, fw, fb, out);
    last_kernel<<<256, 256, 0, stream>>>(rnn_out, x_out, hn_last, x_last);
}